// Round 15
// baseline (133.023 us; speedup 1.0000x reference)
//
#include <hip/hip_runtime.h>
#include <stdint.h>
#include <math.h>

#define HFM 64
#define WFM 128
#define CFM 128
#define BN 2
#define HWFM (HFM*WFM)          // 8192
#define NPIX (BN*HWFM)          // 16384
#define KQ 6000
#define KQP 6144                // padded to 48*128 (rows 6000..6143 zero)
#define NNEG 60
#define NE (NPIX*NNEG)          // 983040
#define EHALF_U 491520u
#define MSHIFT 15.0f
#define LOG2E 1.4426950408889634f
#define BSTRIDE 136             // LDS row stride in f16 (272 B, 16B-aligned)

typedef _Float16 f16_8 __attribute__((ext_vector_type(8)));
typedef _Float16 f16_2 __attribute__((ext_vector_type(2)));
typedef float f32_4 __attribute__((ext_vector_type(4)));

// ---------------- JAX threefry2x32 (bit-exact) ----------------
__host__ __device__ __forceinline__ void threefry2x32(uint32_t k0, uint32_t k1,
                                                      uint32_t x0, uint32_t x1,
                                                      uint32_t* o0, uint32_t* o1) {
  uint32_t ks2 = k0 ^ k1 ^ 0x1BD11BDAu;
  x0 += k0; x1 += k1;
#define TFR(r) { x0 += x1; x1 = (x1 << (r)) | (x1 >> (32 - (r))); x1 ^= x0; }
  TFR(13) TFR(15) TFR(26) TFR(6)
  x0 += k1;  x1 += ks2 + 1u;
  TFR(17) TFR(29) TFR(16) TFR(24)
  x0 += ks2; x1 += k0 + 2u;
  TFR(13) TFR(15) TFR(26) TFR(6)
  x0 += k0;  x1 += k1 + 3u;
  TFR(17) TFR(29) TFR(16) TFR(24)
  x0 += k1;  x1 += ks2 + 4u;
  TFR(13) TFR(15) TFR(26) TFR(6)
  x0 += ks2; x1 += k0 + 5u;
#undef TFR
  *o0 = x0; *o1 = x1;
}

// grid_sample coordinate helper (reference op order)
__device__ __forceinline__ void gs_coord(float t, float halfdim, float maxc,
                                         int* i0, int* i1, float* w) {
  float g = 2.0f * t - 1.0f;
  float x = (g + 1.0f) * halfdim - 0.5f;
  x = fminf(fmaxf(x, 0.0f), maxc);
  float f = floorf(x);
  *i0 = (int)f;
  *w = x - f;
  *i1 = (int)fminf(f + 1.0f, maxc);
}

// ====== k_A: mask (first, latency-bound) + qprep + qtrans + transpose ======
__global__ __launch_bounds__(256) void k_A(
    const float* __restrict__ ref, const float* __restrict__ tgt,
    const float* __restrict__ queue,
    const float* __restrict__ target_l, const float* __restrict__ target_r,
    _Float16* __restrict__ refTf, _Float16* __restrict__ tgtTf,
    _Float16* __restrict__ queueTf, float2* __restrict__ qeb,
    float* __restrict__ maskArr, float* __restrict__ xr) {
  __shared__ float tile[32][33];
  int blk = blockIdx.x;
  int tid = threadIdx.x;
  if (blk < 64) {
    // mask: one thread per pixel
    int p = blk * 256 + tid;
    int b = p >> 13;
    int rem = p & (HWFM - 1);
    int i = rem >> 7, j = rem & 127;
    const float stepx = 1.0f / 127.0f, stepy = 1.0f / 63.0f;
    float xb = (j == 127) ? 1.0f : j * stepx;
    float yb = (i == 63) ? 1.0f : i * stepy;
    const float* tl = target_l + (size_t)b * 256 * 512;
    const float* tr = target_r + (size_t)b * 256 * 512;
    float dl = tl[(4 * i) * 512 + 4 * j] * 0.25f;
    int y0i, y1i; float wy;
    gs_coord(yb, 32.0f, 63.0f, &y0i, &y1i, &wy);
    float t = xb - dl * (1.0f / 128.0f);
    int x0i, x1i; float wx;
    gs_coord(t, 64.0f, 127.0f, &x0i, &x1i, &wx);
    auto innerv = [&](int y, int x) -> float {
      float xbx = (x == 127) ? 1.0f : x * stepx;
      float drv = tr[(4 * y) * 512 + 4 * x] * 0.25f;
      float ti = xbx + drv * (1.0f / 128.0f);
      float g = 2.0f * ti - 1.0f;
      float ix2 = fminf(fmaxf((g + 1.0f) * 64.0f - 0.5f, 0.0f), 127.0f);
      float x0f = floorf(ix2);
      float wxp = ix2 - x0f;
      float x1f = fminf(x0f + 1.0f, 127.0f);
      return x0f * (1.0f - wxp) + x1f * wxp;
    };
    float v00 = innerv(y0i, x0i), v01 = innerv(y0i, x1i);
    float v10 = innerv(y1i, x0i), v11 = innerv(y1i, x1i);
    float l2r2l = v00 * (1.0f - wx) * (1.0f - wy) + v01 * wx * (1.0f - wy)
                + v10 * (1.0f - wx) * wy + v11 * wx * wy;
    bool masko = fabsf((float)j - l2r2l) < 3.0f;
    bool mk = masko && (dl > 0.0f) && (t >= 0.0f);
    maskArr[p] = mk ? 1.0f : 0.0f;
    xr[p] = t * 128.0f;   // exact: t*2^7
  } else if (blk < 88) {
    int k = (blk - 64) * 256 + tid;
    if (k < KQP) {
      if (k >= KQ) { qeb[k] = make_float2(0.0f, -1000.0f); }
      else {
        float ss = 0.0f;
        for (int c = 0; c < CFM; c++) { float v = queue[c * KQ + k]; ss += v * v; }
        float qi = 1.0f / fmaxf(sqrtf(ss), 1e-12f);
        qeb[k] = make_float2(qi * (LOG2E / 0.07f), -MSHIFT * LOG2E);
      }
    }
  } else if (blk < 856) {
    int q = blk - 88;
    int cy = q / 192, nx = q - cy * 192;
    int n0 = nx * 32, c0 = cy * 32;
    int tx = tid & 31, ty = tid >> 5;
#pragma unroll
    for (int i = 0; i < 32; i += 8) {
      int n = n0 + tx;
      tile[ty + i][tx] = (n < KQ) ? queue[(size_t)(c0 + ty + i) * KQ + n] : 0.0f;
    }
    __syncthreads();
#pragma unroll
    for (int i = 0; i < 32; i += 8)
      queueTf[(size_t)(n0 + ty + i) * CFM + (c0 + tx)] = (_Float16)tile[tx][ty + i];
  } else {
    int fblk = blk - 856;
    int z = fblk >> 10, yb_ = (fblk >> 8) & 3, xb_ = fblk & 255;
    int arr = z >> 1, b = z & 1;
    const float* src = (arr == 0 ? ref : tgt) + (size_t)b * CFM * HWFM;
    _Float16* dst = (arr == 0 ? refTf : tgtTf) + (size_t)b * HWFM * CFM;
    int x0 = xb_ * 32, y0 = yb_ * 32;
    int tx = tid & 31, ty = tid >> 5;
#pragma unroll
    for (int i = 0; i < 32; i += 8)
      tile[ty + i][tx] = src[(size_t)(y0 + ty + i) * HWFM + x0 + tx];
    __syncthreads();
#pragma unroll
    for (int i = 0; i < 32; i += 8)
      dst[(size_t)(x0 + ty + i) * CFM + (y0 + tx)] = (_Float16)tile[tx][ty + i];
  }
}

// ========== k_compact: single block ballot + prefix scan (ascending) ==========
__global__ __launch_bounds__(256) void k_compact(const float* __restrict__ maskArr,
                                                 int* __restrict__ count,
                                                 int* __restrict__ list) {
  __shared__ int wsum[4];
  int tid = threadIdx.x;
  int lane = tid & 63, wave = tid >> 6;
  int base_p = tid * 64;
  unsigned long long bits = 0ull;
  const float4* m4 = (const float4*)(maskArr + base_p);
#pragma unroll
  for (int k = 0; k < 16; k++) {
    float4 v = m4[k];
    if (v.x > 0.0f) bits |= 1ull << (4 * k + 0);
    if (v.y > 0.0f) bits |= 1ull << (4 * k + 1);
    if (v.z > 0.0f) bits |= 1ull << (4 * k + 2);
    if (v.w > 0.0f) bits |= 1ull << (4 * k + 3);
  }
  int m = __popcll(bits);
  int scan = m;
#pragma unroll
  for (int off = 1; off < 64; off <<= 1) {
    int n = __shfl_up(scan, off, 64);
    if (lane >= off) scan += n;
  }
  if (lane == 63) wsum[wave] = scan;
  __syncthreads();
  int wbase = 0;
  for (int w = 0; w < wave; w++) wbase += wsum[w];
  int idx = wbase + scan - m;
  for (int k = 0; k < 64; k++) {
    if ((bits >> k) & 1ull) list[idx++] = base_p + k;
  }
  if (tid == 255) *count = idx;
}

// ====== k_B: colstats (blocks 0..63) + slot-indexed prelude (writes QTfc) ======
__global__ __launch_bounds__(256) void k_B(
    const _Float16* __restrict__ refTf, const _Float16* __restrict__ tgtTf,
    _Float16* __restrict__ QTfc, float* __restrict__ stats,
    const float* __restrict__ xr,
    float* __restrict__ S, float* __restrict__ logit0,
    const int* __restrict__ count, const int* __restrict__ list) {
  int blk = blockIdx.x;
  int tid = threadIdx.x;
  int lane = tid & 63;
  if (blk < 64) {
    int sub = tid >> 6;
    int xg = blk * 4 + sub;
    int b = xg >> 7, x = xg & 127;
    int xp = min(x + 1, 127);
    int c2 = lane * 2;
    int base = b * HWFM;
    f16_2 c0  = *(const f16_2*)(tgtTf + (size_t)(base + x) * CFM + c2);
    f16_2 c1  = *(const f16_2*)(tgtTf + (size_t)(base + WFM + x) * CFM + c2);
    f16_2 c0p = *(const f16_2*)(tgtTf + (size_t)(base + xp) * CFM + c2);
    f16_2 c1p = *(const f16_2*)(tgtTf + (size_t)(base + WFM + xp) * CFM + c2);
    float a0 = (float)c0[0], a1 = (float)c0[1];
    float b0 = (float)c1[0], b1 = (float)c1[1];
    float p0 = (float)c0p[0], p1 = (float)c0p[1];
    float q0 = (float)c1p[0], q1 = (float)c1p[1];
    float s[7];
    s[0] = a0 * a0 + a1 * a1;
    s[1] = a0 * b0 + a1 * b1;
    s[2] = b0 * b0 + b1 * b1;
    s[3] = a0 * p0 + a1 * p1;
    s[4] = a0 * q0 + a1 * q1;
    s[5] = b0 * p0 + b1 * p1;
    s[6] = b0 * q0 + b1 * q1;
#pragma unroll
    for (int o = 32; o; o >>= 1)
#pragma unroll
      for (int k = 0; k < 7; k++) s[k] += __shfl_xor(s[k], o, 64);
    if (lane == 0) {
      float* st = stats + (size_t)xg * 8;
#pragma unroll
      for (int k = 0; k < 7; k++) st[k] = s[k];
      st[7] = 0.0f;
    }
  } else {
    // prelude: wave per compacted slot
    int wave = tid >> 6;
    int cnt = *count;
    int slot = (blk - 64) * 4 + wave;
    if (slot >= cnt) return;
    int p = list[slot];
    int b = p >> 13;
    int rem = p & (HWFM - 1);
    int i = rem >> 7;
    const float stepy = 1.0f / 63.0f;
    float yb = (i == 63) ? 1.0f : i * stepy;
    float t = xr[p] * (1.0f / 128.0f);   // exact recovery
    int y0i, y1i; float wy;
    gs_coord(yb, 32.0f, 63.0f, &y0i, &y1i, &wy);
    int x0i, x1i; float wx;
    gs_coord(t, 64.0f, 127.0f, &x0i, &x1i, &wx);

    int c2 = lane * 2;
    f16_2 q2 = *(const f16_2*)(refTf + (size_t)p * CFM + c2);
    int bo = b * HWFM;
    f16_2 a2 = *(const f16_2*)(tgtTf + (size_t)(bo + y0i * WFM + x0i) * CFM + c2);
    f16_2 b2 = *(const f16_2*)(tgtTf + (size_t)(bo + y0i * WFM + x1i) * CFM + c2);
    f16_2 cc2 = *(const f16_2*)(tgtTf + (size_t)(bo + y1i * WFM + x0i) * CFM + c2);
    f16_2 d2 = *(const f16_2*)(tgtTf + (size_t)(bo + y1i * WFM + x1i) * CFM + c2);

    float w00 = (1.0f - wx) * (1.0f - wy), w01 = wx * (1.0f - wy);
    float w10 = (1.0f - wx) * wy,          w11 = wx * wy;
    float q0 = (float)q2[0], q1 = (float)q2[1];
    float v0 = w00 * (float)a2[0] + w01 * (float)b2[0] + w10 * (float)cc2[0] + w11 * (float)d2[0];
    float v1 = w00 * (float)a2[1] + w01 * (float)b2[1] + w10 * (float)cc2[1] + w11 * (float)d2[1];

    float s0 = q0 * q0 + q1 * q1;
    float s1 = q0 * v0 + q1 * v1;
    float s2 = v0 * v0 + v1 * v1;
#pragma unroll
    for (int o = 32; o; o >>= 1) {
      s0 += __shfl_xor(s0, o, 64);
      s1 += __shfl_xor(s1, o, 64);
      s2 += __shfl_xor(s2, o, 64);
    }
    float inv = 1.0f / fmaxf(sqrtf(s0), 1e-12f);
    f16_2 qw; qw[0] = (_Float16)(q0 * inv); qw[1] = (_Float16)(q1 * inv);
    *(f16_2*)(QTfc + (size_t)slot * CFM + c2) = qw;   // compacted row
    if (lane == 0) {
      float lpos = (s1 * inv) / fmaxf(sqrtf(s2), 1e-12f);
      float lg0 = lpos / 0.07f;
      logit0[p] = lg0;
      S[p] = expf(lg0 - MSHIFT);
    }
  }
}

// ======== k_gemm: 64-row tile, single 35KB LDS buffer + reg-prefetch ========
// grid (12, 256): 4 l_q chunks/block; x-blocks 0..3 prepend one D chunk.
// Pipeline per stage: write_lds(regs) -> sync -> prefetch next to regs ->
// MFMA from LDS -> sync.  ~3-4 blocks/CU resident to cover barriers.
__global__ __launch_bounds__(256) void k_gemm(
    const _Float16* __restrict__ QTfc,    // [cnt][128] compacted queries
    const _Float16* __restrict__ queueTf, // [6144][128]
    const _Float16* __restrict__ tgtTf,   // [NPIX][128]
    const float2* __restrict__ qeb,       // [6144]
    float* __restrict__ S, _Float16* __restrict__ Dh,
    const int* __restrict__ count, const int* __restrict__ list) {
  __shared__ _Float16 Bs[128 * BSTRIDE];   // 34816 B
  __shared__ float Srow[64];
  __shared__ int pb[64];
  int tid = threadIdx.x;
  int cnt = *count;
  int pblk = blockIdx.y * 64;
  if (pblk >= cnt) return;
  int wave = tid >> 6, lane = tid & 63;
  int quad = lane >> 4, l16 = lane & 15;
  int wm = wave >> 1, wn = wave & 1;

  if (tid < 64) {
    Srow[tid] = 0.0f;
    pb[tid] = list[min(pblk + tid, cnt - 1)] >> 13;
  }

  // A fragments from compacted rows (clamped; overflow rows' results discarded)
  f16_8 Af[2][4];
  int r0 = pblk + wm * 32;
#pragma unroll
  for (int mt = 0; mt < 2; mt++) {
    const _Float16* arow = QTfc + (size_t)min(r0 + mt * 16 + l16, cnt - 1) * CFM + quad * 8;
#pragma unroll
    for (int ks = 0; ks < 4; ks++)
      Af[mt][ks] = *(const f16_8*)(arow + ks * 32);
  }

  f16_8 sreg[8];
  int srow[8], sc16[8];
#pragma unroll
  for (int it = 0; it < 8; it++) {
    int idx = it * 256 + tid;
    srow[it] = idx >> 4; sc16[it] = idx & 15;
  }
  auto load_src = [&](const _Float16* bsrc) {
#pragma unroll
    for (int it = 0; it < 8; it++)
      sreg[it] = *(const f16_8*)(bsrc + (size_t)srow[it] * CFM + sc16[it] * 8);
  };
  auto write_lds = [&]() {
#pragma unroll
    for (int it = 0; it < 8; it++)
      *(f16_8*)(&Bs[srow[it] * BSTRIDE + sc16[it] * 8]) = sreg[it];
  };

  int nbase = blockIdx.x * 4 * 128;   // x in [0,12): 4 chunks each
  bool hasD = blockIdx.x < 4;
  float rowsum[2][4] = {{0.0f,0.0f,0.0f,0.0f},{0.0f,0.0f,0.0f,0.0f}};

  // prologue: load first stage source into regs
  if (hasD) {
    int batch = blockIdx.x >> 1;
    load_src(tgtTf + ((size_t)batch * HWFM + (blockIdx.x & 1) * 128) * CFM);
  } else {
    load_src(queueTf + (size_t)nbase * CFM);
  }

  // ---- D stage (x-blocks 0..3) ----
  if (hasD) {
    write_lds();
    __syncthreads();
    load_src(queueTf + (size_t)nbase * CFM);   // prefetch l_q chunk 0
    int batch = blockIdx.x >> 1;
    f32_4 acc[2][4];
#pragma unroll
    for (int mt = 0; mt < 2; mt++)
#pragma unroll
      for (int nt = 0; nt < 4; nt++)
        acc[mt][nt] = (f32_4){0.0f, 0.0f, 0.0f, 0.0f};
#pragma unroll
    for (int ks = 0; ks < 4; ks++) {
      f16_8 Bk[4];
#pragma unroll
      for (int nt = 0; nt < 4; nt++)
        Bk[nt] = *(const f16_8*)(&Bs[(wn * 64 + nt * 16 + l16) * BSTRIDE + ks * 32 + quad * 8]);
#pragma unroll
      for (int mt = 0; mt < 2; mt++)
#pragma unroll
        for (int nt = 0; nt < 4; nt++)
          acc[mt][nt] = __builtin_amdgcn_mfma_f32_16x16x32_f16(Af[mt][ks], Bk[nt], acc[mt][nt], 0, 0, 0);
    }
#pragma unroll
    for (int mt = 0; mt < 2; mt++)
#pragma unroll
      for (int nt = 0; nt < 4; nt++)
#pragma unroll
        for (int r = 0; r < 4; r++) {
          int rowloc = wm * 32 + mt * 16 + quad * 4 + r;
          int slot = pblk + rowloc;
          int colL = (blockIdx.x & 1) * 128 + wn * 64 + nt * 16 + l16;
          if (slot < cnt && pb[rowloc] == batch)
            Dh[(size_t)slot * 256 + colL] = (_Float16)acc[mt][nt][r];
        }
    __syncthreads();
  }

  // ---- l_q stages: sreg holds chunk ic at loop entry ----
#pragma unroll
  for (int ic = 0; ic < 4; ic++) {
    int n0 = nbase + ic * 128;
    write_lds();
    __syncthreads();
    if (ic < 3) load_src(queueTf + (size_t)(n0 + 128) * CFM);   // prefetch
    float2 qb[4];
#pragma unroll
    for (int nt = 0; nt < 4; nt++) qb[nt] = qeb[n0 + wn * 64 + nt * 16 + l16];

    f32_4 acc[2][4];
#pragma unroll
    for (int mt = 0; mt < 2; mt++)
#pragma unroll
      for (int nt = 0; nt < 4; nt++)
        acc[mt][nt] = (f32_4){0.0f, 0.0f, 0.0f, 0.0f};
#pragma unroll
    for (int ks = 0; ks < 4; ks++) {
      f16_8 Bk[4];
#pragma unroll
      for (int nt = 0; nt < 4; nt++)
        Bk[nt] = *(const f16_8*)(&Bs[(wn * 64 + nt * 16 + l16) * BSTRIDE + ks * 32 + quad * 8]);
#pragma unroll
      for (int mt = 0; mt < 2; mt++)
#pragma unroll
        for (int nt = 0; nt < 4; nt++)
          acc[mt][nt] = __builtin_amdgcn_mfma_f32_16x16x32_f16(Af[mt][ks], Bk[nt], acc[mt][nt], 0, 0, 0);
    }
#pragma unroll
    for (int nt = 0; nt < 4; nt++)
#pragma unroll
      for (int mt = 0; mt < 2; mt++)
#pragma unroll
        for (int r = 0; r < 4; r++)
          rowsum[mt][r] += exp2f(fmaf(acc[mt][nt][r], qb[nt].x, qb[nt].y));
    __syncthreads();
  }

#pragma unroll
  for (int mt = 0; mt < 2; mt++)
#pragma unroll
    for (int r = 0; r < 4; r++) {
      float vv = rowsum[mt][r];
      vv += __shfl_xor(vv, 1);
      vv += __shfl_xor(vv, 2);
      vv += __shfl_xor(vv, 4);
      vv += __shfl_xor(vv, 8);
      rowsum[mt][r] = vv;
    }
  if (l16 == 0) {
#pragma unroll
    for (int mt = 0; mt < 2; mt++)
#pragma unroll
      for (int r = 0; r < 4; r++)
        atomicAdd(&Srow[wm * 32 + mt * 16 + quad * 4 + r], rowsum[mt][r]);
  }
  __syncthreads();
  if (tid < 64) {
    int pr = pblk + tid;
    if (pr < cnt) atomicAdd(&S[list[pr]], Srow[tid]);
  }
}

// -------- negatives: wave-per-pixel, scalar via f16 D + stats decomposition --
__global__ __launch_bounds__(256) void k_negatives_lite(
    const _Float16* __restrict__ Dh, const float* __restrict__ stats,
    const float* __restrict__ xr, float* __restrict__ S,
    const int* __restrict__ count, const int* __restrict__ list,
    uint32_t k1a, uint32_t k1b, uint32_t k2a, uint32_t k2b) {
  int tid = threadIdx.x;
  int wave = tid >> 6, lane = tid & 63;
  int cnt = *count;
  int slot = blockIdx.x * 4 + wave;
  if (slot >= cnt) return;
  int p = list[slot];
  int b = p >> 13;
  float esum = 0.0f;
  if (lane < NNEG) {
    uint32_t e = (uint32_t)(p * NNEG + lane);
    uint32_t h0, h1;
    threefry2x32(k1a, k1b, e, e + (uint32_t)NE, &h0, &h1);
    uint32_t off = ((h0 % 24u) * 16u + (h1 % 24u)) % 24u;
    float mag = (float)(1u + off);
    uint32_t ub;
    {
      uint32_t a, bm;
      if (e < EHALF_U) { threefry2x32(k2a, k2b, e, e + EHALF_U, &a, &bm); ub = a; }
      else             { threefry2x32(k2a, k2b, e - EHALF_U, e, &a, &bm); ub = bm; }
    }
    float u = __uint_as_float((ub >> 9) | 0x3F800000u) - 1.0f;
    float sg = (u > 0.5f) ? 1.0f : ((u < 0.5f) ? -1.0f : 0.0f);

    float v = xr[p] + mag * sg;
    float r = fmodf(v, 128.0f);
    if (r < 0.0f) r += 128.0f;
    float fx = r * (1.0f / 128.0f);
    float fy = fx * (1.0f / 64.0f);
    int x0i, x1i, y0i, y1i; float wx, wy;
    gs_coord(fx, 64.0f, 127.0f, &x0i, &x1i, &wx);
    gs_coord(fy, 32.0f, 63.0f, &y0i, &y1i, &wy);

    const _Float16* Dp = Dh + (size_t)slot * 256;
    float d00 = (float)Dp[x0i], d01 = (float)Dp[x1i];
    float d10 = (float)Dp[128 + x0i], d11 = (float)Dp[128 + x1i];
    float u0 = 1.0f - wy, u1 = wy;
    float dv0 = u0 * d00 + u1 * d10;
    float dv1 = u0 * d01 + u1 * d11;
    float dot = (1.0f - wx) * dv0 + wx * dv1;

    const float* st0 = stats + (size_t)(b * 128 + x0i) * 8;
    const float* st1 = stats + (size_t)(b * 128 + x1i) * 8;
    float4 sa = *(const float4*)st0;
    float4 sb = *(const float4*)(st0 + 4);
    float4 sc = *(const float4*)st1;
    float a0 = u0 * u0, a1 = u0 * u1, a2 = u1 * u1;
    float nB0 = a0 * sa.x + 2.0f * a1 * sa.y + a2 * sa.z;
    float nB1 = a0 * sc.x + 2.0f * a1 * sc.y + a2 * sc.z;
    float cB  = a0 * sa.w + a1 * (sb.x + sb.y) + a2 * sb.z;
    float wx0 = 1.0f - wx;
    float nsq = wx0 * wx0 * nB0 + 2.0f * wx * wx0 * cB + wx * wx * nB1;
    float ln = dot / fmaxf(sqrtf(fmaxf(nsq, 0.0f)), 1e-12f);
    esum = __expf(ln * (1.0f / 0.07f) - MSHIFT);
  }
#pragma unroll
  for (int o = 32; o; o >>= 1) esum += __shfl_xor(esum, o, 64);
  if (lane == 0) atomicAdd(&S[p], esum);
}

__global__ __launch_bounds__(1024) void k_finalize(
    const float* __restrict__ S, const float* __restrict__ logit0,
    const float* __restrict__ maskArr, float* __restrict__ out) {
  int tid = threadIdx.x;
  const float cmask = logf(6061.0f);
  double acc = 0.0;
  for (int p = tid; p < NPIX; p += 1024) {
    float term = (maskArr[p] > 0.0f) ? (logf(S[p]) + MSHIFT - logit0[p]) : cmask;
    acc += (double)term;
  }
#pragma unroll
  for (int off = 32; off; off >>= 1) acc += __shfl_down(acc, off, 64);
  __shared__ double sd[16];
  if ((tid & 63) == 0) sd[tid >> 6] = acc;
  __syncthreads();
  if (tid == 0) {
    double tot = 0.0;
    for (int w = 0; w < 16; w++) tot += sd[w];
    out[0] = (float)(tot / (double)NPIX);
  }
}

extern "C" void kernel_launch(void* const* d_in, const int* in_sizes, int n_in,
                              void* d_out, int out_size, void* d_ws, size_t ws_size,
                              hipStream_t stream) {
  const float* ref   = (const float*)d_in[0];
  const float* tgt   = (const float*)d_in[1];
  const float* tl    = (const float*)d_in[2];
  const float* tr    = (const float*)d_in[3];
  const float* queue = (const float*)d_in[4];
  float* out = (float*)d_out;
  float* ws = (float*)d_ws;

  float2* qeb = (float2*)ws;                 // 6144 float2 -> 12288 floats
  float* S    = ws + 12288;                  // 16384
  float* lg0  = ws + 28672;                  // 16384
  float* mk   = ws + 45056;                  // 16384
  float* xr   = ws + 61440;                  // 16384 -> 77824
  int* count  = (int*)(ws + 77824);          // 1
  int* list   = (int*)(ws + 77840);          // 16384 -> 94224
  _Float16* QTfc    = (_Float16*)(ws + 94464);    // NPIX*128 f16 (compacted rows)
  _Float16* queueTf = (_Float16*)(ws + 1143040);  // 6144*128 f16
  _Float16* tgtTf   = (_Float16*)(ws + 1536256);  // NPIX*128 f16
  _Float16* refTf   = (_Float16*)(ws + 2584832);  // NPIX*128 f16
  float* stats = ws + 3633408;                    // 2048
  _Float16* Dh = (_Float16*)(ws + 3635456);       // NPIX*256 f16

  // JAX: k1, k2 = split(key(1234))
  uint32_t b0o0, b0o1, b1o0, b1o1;
  threefry2x32(0u, 1234u, 0u, 2u, &b0o0, &b0o1);
  threefry2x32(0u, 1234u, 1u, 3u, &b1o0, &b1o1);
  uint32_t k1a = b0o0, k1b = b1o0, k2a = b0o1, k2b = b1o1;

  k_A<<<dim3(4952), dim3(256), 0, stream>>>(ref, tgt, queue, tl, tr,
                                            refTf, tgtTf, queueTf, qeb, mk, xr);
  k_compact<<<dim3(1), dim3(256), 0, stream>>>(mk, count, list);
  k_B<<<dim3(64 + 4096), dim3(256), 0, stream>>>(refTf, tgtTf, QTfc, stats,
                                                 xr, S, lg0, count, list);
  k_gemm<<<dim3(12, NPIX / 64), dim3(256), 0, stream>>>(QTfc, queueTf, tgtTf, qeb,
                                                        S, Dh, count, list);
  k_negatives_lite<<<dim3(NPIX / 4), dim3(256), 0, stream>>>(Dh, stats, xr, S, count, list,
                                                             k1a, k1b, k2a, k2b);
  k_finalize<<<dim3(1), dim3(1024), 0, stream>>>(S, lg0, mk, out);
}

// Round 16
// 132.839 us; speedup vs baseline: 1.0014x; 1.0014x over previous
//
#include <hip/hip_runtime.h>
#include <stdint.h>
#include <math.h>

#define HFM 64
#define WFM 128
#define CFM 128
#define BN 2
#define HWFM (HFM*WFM)          // 8192
#define NPIX (BN*HWFM)          // 16384
#define KQ 6000
#define KQP 6144                // padded to 48*128 (rows 6000..6143 zero)
#define NNEG 60
#define NE (NPIX*NNEG)          // 983040
#define EHALF_U 491520u
#define MSHIFT 15.0f
#define LOG2E 1.4426950408889634f
#define BSTRIDE 128             // LDS row stride in f16 (256 B) + XOR swizzle

typedef _Float16 f16_8 __attribute__((ext_vector_type(8)));
typedef _Float16 f16_2 __attribute__((ext_vector_type(2)));
typedef float f32_4 __attribute__((ext_vector_type(4)));

// ---------------- JAX threefry2x32 (bit-exact) ----------------
__host__ __device__ __forceinline__ void threefry2x32(uint32_t k0, uint32_t k1,
                                                      uint32_t x0, uint32_t x1,
                                                      uint32_t* o0, uint32_t* o1) {
  uint32_t ks2 = k0 ^ k1 ^ 0x1BD11BDAu;
  x0 += k0; x1 += k1;
#define TFR(r) { x0 += x1; x1 = (x1 << (r)) | (x1 >> (32 - (r))); x1 ^= x0; }
  TFR(13) TFR(15) TFR(26) TFR(6)
  x0 += k1;  x1 += ks2 + 1u;
  TFR(17) TFR(29) TFR(16) TFR(24)
  x0 += ks2; x1 += k0 + 2u;
  TFR(13) TFR(15) TFR(26) TFR(6)
  x0 += k0;  x1 += k1 + 3u;
  TFR(17) TFR(29) TFR(16) TFR(24)
  x0 += k1;  x1 += ks2 + 4u;
  TFR(13) TFR(15) TFR(26) TFR(6)
  x0 += ks2; x1 += k0 + 5u;
#undef TFR
  *o0 = x0; *o1 = x1;
}

// grid_sample coordinate helper (reference op order)
__device__ __forceinline__ void gs_coord(float t, float halfdim, float maxc,
                                         int* i0, int* i1, float* w) {
  float g = 2.0f * t - 1.0f;
  float x = (g + 1.0f) * halfdim - 0.5f;
  x = fminf(fmaxf(x, 0.0f), maxc);
  float f = floorf(x);
  *i0 = (int)f;
  *w = x - f;
  *i1 = (int)fminf(f + 1.0f, maxc);
}

// ====== k_A: mask (first, latency-bound) + qprep + qtrans + transpose ======
__global__ __launch_bounds__(256) void k_A(
    const float* __restrict__ ref, const float* __restrict__ tgt,
    const float* __restrict__ queue,
    const float* __restrict__ target_l, const float* __restrict__ target_r,
    _Float16* __restrict__ refTf, _Float16* __restrict__ tgtTf,
    _Float16* __restrict__ queueTf, float2* __restrict__ qeb,
    float* __restrict__ maskArr, float* __restrict__ xr) {
  __shared__ float tile[32][33];
  int blk = blockIdx.x;
  int tid = threadIdx.x;
  if (blk < 64) {
    // mask: one thread per pixel
    int p = blk * 256 + tid;
    int b = p >> 13;
    int rem = p & (HWFM - 1);
    int i = rem >> 7, j = rem & 127;
    const float stepx = 1.0f / 127.0f, stepy = 1.0f / 63.0f;
    float xb = (j == 127) ? 1.0f : j * stepx;
    float yb = (i == 63) ? 1.0f : i * stepy;
    const float* tl = target_l + (size_t)b * 256 * 512;
    const float* tr = target_r + (size_t)b * 256 * 512;
    float dl = tl[(4 * i) * 512 + 4 * j] * 0.25f;
    int y0i, y1i; float wy;
    gs_coord(yb, 32.0f, 63.0f, &y0i, &y1i, &wy);
    float t = xb - dl * (1.0f / 128.0f);
    int x0i, x1i; float wx;
    gs_coord(t, 64.0f, 127.0f, &x0i, &x1i, &wx);
    auto innerv = [&](int y, int x) -> float {
      float xbx = (x == 127) ? 1.0f : x * stepx;
      float drv = tr[(4 * y) * 512 + 4 * x] * 0.25f;
      float ti = xbx + drv * (1.0f / 128.0f);
      float g = 2.0f * ti - 1.0f;
      float ix2 = fminf(fmaxf((g + 1.0f) * 64.0f - 0.5f, 0.0f), 127.0f);
      float x0f = floorf(ix2);
      float wxp = ix2 - x0f;
      float x1f = fminf(x0f + 1.0f, 127.0f);
      return x0f * (1.0f - wxp) + x1f * wxp;
    };
    float v00 = innerv(y0i, x0i), v01 = innerv(y0i, x1i);
    float v10 = innerv(y1i, x0i), v11 = innerv(y1i, x1i);
    float l2r2l = v00 * (1.0f - wx) * (1.0f - wy) + v01 * wx * (1.0f - wy)
                + v10 * (1.0f - wx) * wy + v11 * wx * wy;
    bool masko = fabsf((float)j - l2r2l) < 3.0f;
    bool mk = masko && (dl > 0.0f) && (t >= 0.0f);
    maskArr[p] = mk ? 1.0f : 0.0f;
    xr[p] = t * 128.0f;   // exact: t*2^7
  } else if (blk < 88) {
    int k = (blk - 64) * 256 + tid;
    if (k < KQP) {
      if (k >= KQ) { qeb[k] = make_float2(0.0f, -1000.0f); }
      else {
        float ss = 0.0f;
        for (int c = 0; c < CFM; c++) { float v = queue[c * KQ + k]; ss += v * v; }
        float qi = 1.0f / fmaxf(sqrtf(ss), 1e-12f);
        qeb[k] = make_float2(qi * (LOG2E / 0.07f), -MSHIFT * LOG2E);
      }
    }
  } else if (blk < 856) {
    int q = blk - 88;
    int cy = q / 192, nx = q - cy * 192;
    int n0 = nx * 32, c0 = cy * 32;
    int tx = tid & 31, ty = tid >> 5;
#pragma unroll
    for (int i = 0; i < 32; i += 8) {
      int n = n0 + tx;
      tile[ty + i][tx] = (n < KQ) ? queue[(size_t)(c0 + ty + i) * KQ + n] : 0.0f;
    }
    __syncthreads();
#pragma unroll
    for (int i = 0; i < 32; i += 8)
      queueTf[(size_t)(n0 + ty + i) * CFM + (c0 + tx)] = (_Float16)tile[tx][ty + i];
  } else {
    int fblk = blk - 856;
    int z = fblk >> 10, yb_ = (fblk >> 8) & 3, xb_ = fblk & 255;
    int arr = z >> 1, b = z & 1;
    const float* src = (arr == 0 ? ref : tgt) + (size_t)b * CFM * HWFM;
    _Float16* dst = (arr == 0 ? refTf : tgtTf) + (size_t)b * HWFM * CFM;
    int x0 = xb_ * 32, y0 = yb_ * 32;
    int tx = tid & 31, ty = tid >> 5;
#pragma unroll
    for (int i = 0; i < 32; i += 8)
      tile[ty + i][tx] = src[(size_t)(y0 + ty + i) * HWFM + x0 + tx];
    __syncthreads();
#pragma unroll
    for (int i = 0; i < 32; i += 8)
      dst[(size_t)(x0 + ty + i) * CFM + (y0 + tx)] = (_Float16)tile[tx][ty + i];
  }
}

// ========== k_compact: single block ballot + prefix scan (ascending) ==========
__global__ __launch_bounds__(256) void k_compact(const float* __restrict__ maskArr,
                                                 int* __restrict__ count,
                                                 int* __restrict__ list) {
  __shared__ int wsum[4];
  int tid = threadIdx.x;
  int lane = tid & 63, wave = tid >> 6;
  int base_p = tid * 64;
  unsigned long long bits = 0ull;
  const float4* m4 = (const float4*)(maskArr + base_p);
#pragma unroll
  for (int k = 0; k < 16; k++) {
    float4 v = m4[k];
    if (v.x > 0.0f) bits |= 1ull << (4 * k + 0);
    if (v.y > 0.0f) bits |= 1ull << (4 * k + 1);
    if (v.z > 0.0f) bits |= 1ull << (4 * k + 2);
    if (v.w > 0.0f) bits |= 1ull << (4 * k + 3);
  }
  int m = __popcll(bits);
  int scan = m;
#pragma unroll
  for (int off = 1; off < 64; off <<= 1) {
    int n = __shfl_up(scan, off, 64);
    if (lane >= off) scan += n;
  }
  if (lane == 63) wsum[wave] = scan;
  __syncthreads();
  int wbase = 0;
  for (int w = 0; w < wave; w++) wbase += wsum[w];
  int idx = wbase + scan - m;
  for (int k = 0; k < 64; k++) {
    if ((bits >> k) & 1ull) list[idx++] = base_p + k;
  }
  if (tid == 255) *count = idx;
}

// ====== k_B: colstats (blocks 0..63) + slot-indexed prelude (writes QTfc) ======
__global__ __launch_bounds__(256) void k_B(
    const _Float16* __restrict__ refTf, const _Float16* __restrict__ tgtTf,
    _Float16* __restrict__ QTfc, float* __restrict__ stats,
    const float* __restrict__ xr,
    float* __restrict__ S, float* __restrict__ logit0,
    const int* __restrict__ count, const int* __restrict__ list) {
  int blk = blockIdx.x;
  int tid = threadIdx.x;
  int lane = tid & 63;
  if (blk < 64) {
    int sub = tid >> 6;
    int xg = blk * 4 + sub;
    int b = xg >> 7, x = xg & 127;
    int xp = min(x + 1, 127);
    int c2 = lane * 2;
    int base = b * HWFM;
    f16_2 c0  = *(const f16_2*)(tgtTf + (size_t)(base + x) * CFM + c2);
    f16_2 c1  = *(const f16_2*)(tgtTf + (size_t)(base + WFM + x) * CFM + c2);
    f16_2 c0p = *(const f16_2*)(tgtTf + (size_t)(base + xp) * CFM + c2);
    f16_2 c1p = *(const f16_2*)(tgtTf + (size_t)(base + WFM + xp) * CFM + c2);
    float a0 = (float)c0[0], a1 = (float)c0[1];
    float b0 = (float)c1[0], b1 = (float)c1[1];
    float p0 = (float)c0p[0], p1 = (float)c0p[1];
    float q0 = (float)c1p[0], q1 = (float)c1p[1];
    float s[7];
    s[0] = a0 * a0 + a1 * a1;
    s[1] = a0 * b0 + a1 * b1;
    s[2] = b0 * b0 + b1 * b1;
    s[3] = a0 * p0 + a1 * p1;
    s[4] = a0 * q0 + a1 * q1;
    s[5] = b0 * p0 + b1 * p1;
    s[6] = b0 * q0 + b1 * q1;
#pragma unroll
    for (int o = 32; o; o >>= 1)
#pragma unroll
      for (int k = 0; k < 7; k++) s[k] += __shfl_xor(s[k], o, 64);
    if (lane == 0) {
      float* st = stats + (size_t)xg * 8;
#pragma unroll
      for (int k = 0; k < 7; k++) st[k] = s[k];
      st[7] = 0.0f;
    }
  } else {
    // prelude: wave per compacted slot
    int wave = tid >> 6;
    int cnt = *count;
    int slot = (blk - 64) * 4 + wave;
    if (slot >= cnt) return;
    int p = list[slot];
    int b = p >> 13;
    int rem = p & (HWFM - 1);
    int i = rem >> 7;
    const float stepy = 1.0f / 63.0f;
    float yb = (i == 63) ? 1.0f : i * stepy;
    float t = xr[p] * (1.0f / 128.0f);   // exact recovery
    int y0i, y1i; float wy;
    gs_coord(yb, 32.0f, 63.0f, &y0i, &y1i, &wy);
    int x0i, x1i; float wx;
    gs_coord(t, 64.0f, 127.0f, &x0i, &x1i, &wx);

    int c2 = lane * 2;
    f16_2 q2 = *(const f16_2*)(refTf + (size_t)p * CFM + c2);
    int bo = b * HWFM;
    f16_2 a2 = *(const f16_2*)(tgtTf + (size_t)(bo + y0i * WFM + x0i) * CFM + c2);
    f16_2 b2 = *(const f16_2*)(tgtTf + (size_t)(bo + y0i * WFM + x1i) * CFM + c2);
    f16_2 cc2 = *(const f16_2*)(tgtTf + (size_t)(bo + y1i * WFM + x0i) * CFM + c2);
    f16_2 d2 = *(const f16_2*)(tgtTf + (size_t)(bo + y1i * WFM + x1i) * CFM + c2);

    float w00 = (1.0f - wx) * (1.0f - wy), w01 = wx * (1.0f - wy);
    float w10 = (1.0f - wx) * wy,          w11 = wx * wy;
    float q0 = (float)q2[0], q1 = (float)q2[1];
    float v0 = w00 * (float)a2[0] + w01 * (float)b2[0] + w10 * (float)cc2[0] + w11 * (float)d2[0];
    float v1 = w00 * (float)a2[1] + w01 * (float)b2[1] + w10 * (float)cc2[1] + w11 * (float)d2[1];

    float s0 = q0 * q0 + q1 * q1;
    float s1 = q0 * v0 + q1 * v1;
    float s2 = v0 * v0 + v1 * v1;
#pragma unroll
    for (int o = 32; o; o >>= 1) {
      s0 += __shfl_xor(s0, o, 64);
      s1 += __shfl_xor(s1, o, 64);
      s2 += __shfl_xor(s2, o, 64);
    }
    float inv = 1.0f / fmaxf(sqrtf(s0), 1e-12f);
    f16_2 qw; qw[0] = (_Float16)(q0 * inv); qw[1] = (_Float16)(q1 * inv);
    *(f16_2*)(QTfc + (size_t)slot * CFM + c2) = qw;   // compacted row
    if (lane == 0) {
      float lpos = (s1 * inv) / fmaxf(sqrtf(s2), 1e-12f);
      float lg0 = lpos / 0.07f;
      logit0[p] = lg0;
      S[p] = expf(lg0 - MSHIFT);
    }
  }
}

// ======== k_gemm: 64-row tile, 8 chunks/block, double-buffered LDS with ========
// XOR-swizzled 256B rows (conflict-free b128 reads). grid (6, 256).
// x-blocks 0..3 prepend one 128-col D chunk (f16 output).
__global__ __launch_bounds__(256) void k_gemm(
    const _Float16* __restrict__ QTfc,    // [cnt][128] compacted queries
    const _Float16* __restrict__ queueTf, // [6144][128]
    const _Float16* __restrict__ tgtTf,   // [NPIX][128]
    const float2* __restrict__ qeb,       // [6144]
    float* __restrict__ S, _Float16* __restrict__ Dh,
    const int* __restrict__ count, const int* __restrict__ list) {
  __shared__ _Float16 Bs[2][128 * BSTRIDE];   // 2 x 32768 B
  __shared__ float Srow[64];
  __shared__ int pb[64];
  int tid = threadIdx.x;
  int cnt = *count;
  int pblk = blockIdx.y * 64;
  if (pblk >= cnt) return;
  int wave = tid >> 6, lane = tid & 63;
  int quad = lane >> 4, l16 = lane & 15;
  int wm = wave >> 1, wn = wave & 1;

  if (tid < 64) {
    Srow[tid] = 0.0f;
    pb[tid] = list[min(pblk + tid, cnt - 1)] >> 13;
  }

  // A fragments from compacted rows (clamped; overflow rows discarded at store)
  f16_8 Af[2][4];
  int r0 = pblk + wm * 32;
#pragma unroll
  for (int mt = 0; mt < 2; mt++) {
    const _Float16* arow = QTfc + (size_t)min(r0 + mt * 16 + l16, cnt - 1) * CFM + quad * 8;
#pragma unroll
    for (int ks = 0; ks < 4; ks++)
      Af[mt][ks] = *(const f16_8*)(arow + ks * 32);
  }

  f16_8 sreg[8];
  int srow[8], scol[8];   // scol = swizzled column (in 8-f16 units)
#pragma unroll
  for (int it = 0; it < 8; it++) {
    int idx = it * 256 + tid;
    int row = idx >> 4, c16 = idx & 15;
    srow[it] = row;
    scol[it] = (c16 ^ (row & 15)) * 8;
  }
  int sc16raw[8];
#pragma unroll
  for (int it = 0; it < 8; it++) sc16raw[it] = ((it * 256 + tid) & 15) * 8;

  auto load_src = [&](const _Float16* bsrc) {
#pragma unroll
    for (int it = 0; it < 8; it++)
      sreg[it] = *(const f16_8*)(bsrc + (size_t)srow[it] * CFM + sc16raw[it]);
  };
  auto write_lds = [&](int buf) {
#pragma unroll
    for (int it = 0; it < 8; it++)
      *(f16_8*)(&Bs[buf][srow[it] * BSTRIDE + scol[it]]) = sreg[it];
  };
  // read B fragment: row rl (rl & 15 == l16), logical col16 = ks*4+quad
  auto read_b = [&](int buf, int rl, int ks) -> f16_8 {
    int col = ((ks * 4 + quad) ^ (rl & 15)) * 8;
    return *(const f16_8*)(&Bs[buf][rl * BSTRIDE + col]);
  };

  int nbase = blockIdx.x * 8 * 128;
  int cur;
  float rowsum[2][4] = {{0.0f,0.0f,0.0f,0.0f},{0.0f,0.0f,0.0f,0.0f}};

  if (blockIdx.x < 4) {
    // D chunk
    int batch = blockIdx.x >> 1;
    load_src(tgtTf + ((size_t)batch * HWFM + (blockIdx.x & 1) * 128) * CFM);
    write_lds(0);
    __syncthreads();
    load_src(queueTf + (size_t)nbase * CFM);   // prefetch l_q chunk 0
    f32_4 acc[2][4];
#pragma unroll
    for (int mt = 0; mt < 2; mt++)
#pragma unroll
      for (int nt = 0; nt < 4; nt++)
        acc[mt][nt] = (f32_4){0.0f, 0.0f, 0.0f, 0.0f};
#pragma unroll
    for (int ks = 0; ks < 4; ks++) {
      f16_8 Bk[4];
#pragma unroll
      for (int nt = 0; nt < 4; nt++)
        Bk[nt] = read_b(0, wn * 64 + nt * 16 + l16, ks);
#pragma unroll
      for (int mt = 0; mt < 2; mt++)
#pragma unroll
        for (int nt = 0; nt < 4; nt++)
          acc[mt][nt] = __builtin_amdgcn_mfma_f32_16x16x32_f16(Af[mt][ks], Bk[nt], acc[mt][nt], 0, 0, 0);
    }
#pragma unroll
    for (int mt = 0; mt < 2; mt++)
#pragma unroll
      for (int nt = 0; nt < 4; nt++)
#pragma unroll
        for (int r = 0; r < 4; r++) {
          int rowloc = wm * 32 + mt * 16 + quad * 4 + r;
          int slot = pblk + rowloc;
          int colL = (blockIdx.x & 1) * 128 + wn * 64 + nt * 16 + l16;
          if (slot < cnt && pb[rowloc] == batch)
            Dh[(size_t)slot * 256 + colL] = (_Float16)acc[mt][nt][r];
        }
    write_lds(1);
    __syncthreads();
    cur = 1;
  } else {
    load_src(queueTf + (size_t)nbase * CFM);
    write_lds(0);
    __syncthreads();
    cur = 0;
  }

#pragma unroll
  for (int ic = 0; ic < 8; ic++) {
    int n0 = nbase + ic * 128;
    if (ic + 1 < 8) load_src(queueTf + (size_t)(n0 + 128) * CFM);
    float2 qb[4];
#pragma unroll
    for (int nt = 0; nt < 4; nt++) qb[nt] = qeb[n0 + wn * 64 + nt * 16 + l16];

    f32_4 acc[2][4];
#pragma unroll
    for (int mt = 0; mt < 2; mt++)
#pragma unroll
      for (int nt = 0; nt < 4; nt++)
        acc[mt][nt] = (f32_4){0.0f, 0.0f, 0.0f, 0.0f};
#pragma unroll
    for (int ks = 0; ks < 4; ks++) {
      f16_8 Bk[4];
#pragma unroll
      for (int nt = 0; nt < 4; nt++)
        Bk[nt] = read_b(cur, wn * 64 + nt * 16 + l16, ks);
#pragma unroll
      for (int mt = 0; mt < 2; mt++)
#pragma unroll
        for (int nt = 0; nt < 4; nt++)
          acc[mt][nt] = __builtin_amdgcn_mfma_f32_16x16x32_f16(Af[mt][ks], Bk[nt], acc[mt][nt], 0, 0, 0);
    }
    if (ic + 1 < 8) write_lds(cur ^ 1);   // vmcnt wait lands here, after compute

#pragma unroll
    for (int nt = 0; nt < 4; nt++)
#pragma unroll
      for (int mt = 0; mt < 2; mt++)
#pragma unroll
        for (int r = 0; r < 4; r++)
          rowsum[mt][r] += exp2f(fmaf(acc[mt][nt][r], qb[nt].x, qb[nt].y));
    __syncthreads();
    cur ^= 1;
  }

#pragma unroll
  for (int mt = 0; mt < 2; mt++)
#pragma unroll
    for (int r = 0; r < 4; r++) {
      float vv = rowsum[mt][r];
      vv += __shfl_xor(vv, 1);
      vv += __shfl_xor(vv, 2);
      vv += __shfl_xor(vv, 4);
      vv += __shfl_xor(vv, 8);
      rowsum[mt][r] = vv;
    }
  if (l16 == 0) {
#pragma unroll
    for (int mt = 0; mt < 2; mt++)
#pragma unroll
      for (int r = 0; r < 4; r++)
        atomicAdd(&Srow[wm * 32 + mt * 16 + quad * 4 + r], rowsum[mt][r]);
  }
  __syncthreads();
  if (tid < 64) {
    int pr = pblk + tid;
    if (pr < cnt) atomicAdd(&S[list[pr]], Srow[tid]);
  }
}

// -------- negatives: wave-per-pixel, scalar via f16 D + stats decomposition --
__global__ __launch_bounds__(256) void k_negatives_lite(
    const _Float16* __restrict__ Dh, const float* __restrict__ stats,
    const float* __restrict__ xr, float* __restrict__ S,
    const int* __restrict__ count, const int* __restrict__ list,
    uint32_t k1a, uint32_t k1b, uint32_t k2a, uint32_t k2b) {
  int tid = threadIdx.x;
  int wave = tid >> 6, lane = tid & 63;
  int cnt = *count;
  int slot = blockIdx.x * 4 + wave;
  if (slot >= cnt) return;
  int p = list[slot];
  int b = p >> 13;
  float esum = 0.0f;
  if (lane < NNEG) {
    uint32_t e = (uint32_t)(p * NNEG + lane);
    uint32_t h0, h1;
    threefry2x32(k1a, k1b, e, e + (uint32_t)NE, &h0, &h1);
    uint32_t off = ((h0 % 24u) * 16u + (h1 % 24u)) % 24u;
    float mag = (float)(1u + off);
    uint32_t ub;
    {
      uint32_t a, bm;
      if (e < EHALF_U) { threefry2x32(k2a, k2b, e, e + EHALF_U, &a, &bm); ub = a; }
      else             { threefry2x32(k2a, k2b, e - EHALF_U, e, &a, &bm); ub = bm; }
    }
    float u = __uint_as_float((ub >> 9) | 0x3F800000u) - 1.0f;
    float sg = (u > 0.5f) ? 1.0f : ((u < 0.5f) ? -1.0f : 0.0f);

    float v = xr[p] + mag * sg;
    float r = fmodf(v, 128.0f);
    if (r < 0.0f) r += 128.0f;
    float fx = r * (1.0f / 128.0f);
    float fy = fx * (1.0f / 64.0f);
    int x0i, x1i, y0i, y1i; float wx, wy;
    gs_coord(fx, 64.0f, 127.0f, &x0i, &x1i, &wx);
    gs_coord(fy, 32.0f, 63.0f, &y0i, &y1i, &wy);

    const _Float16* Dp = Dh + (size_t)slot * 256;
    float d00 = (float)Dp[x0i], d01 = (float)Dp[x1i];
    float d10 = (float)Dp[128 + x0i], d11 = (float)Dp[128 + x1i];
    float u0 = 1.0f - wy, u1 = wy;
    float dv0 = u0 * d00 + u1 * d10;
    float dv1 = u0 * d01 + u1 * d11;
    float dot = (1.0f - wx) * dv0 + wx * dv1;

    const float* st0 = stats + (size_t)(b * 128 + x0i) * 8;
    const float* st1 = stats + (size_t)(b * 128 + x1i) * 8;
    float4 sa = *(const float4*)st0;
    float4 sb = *(const float4*)(st0 + 4);
    float4 sc = *(const float4*)st1;
    float a0 = u0 * u0, a1 = u0 * u1, a2 = u1 * u1;
    float nB0 = a0 * sa.x + 2.0f * a1 * sa.y + a2 * sa.z;
    float nB1 = a0 * sc.x + 2.0f * a1 * sc.y + a2 * sc.z;
    float cB  = a0 * sa.w + a1 * (sb.x + sb.y) + a2 * sb.z;
    float wx0 = 1.0f - wx;
    float nsq = wx0 * wx0 * nB0 + 2.0f * wx * wx0 * cB + wx * wx * nB1;
    float ln = dot / fmaxf(sqrtf(fmaxf(nsq, 0.0f)), 1e-12f);
    esum = __expf(ln * (1.0f / 0.07f) - MSHIFT);
  }
#pragma unroll
  for (int o = 32; o; o >>= 1) esum += __shfl_xor(esum, o, 64);
  if (lane == 0) atomicAdd(&S[p], esum);
}

__global__ __launch_bounds__(1024) void k_finalize(
    const float* __restrict__ S, const float* __restrict__ logit0,
    const float* __restrict__ maskArr, float* __restrict__ out) {
  int tid = threadIdx.x;
  const float cmask = logf(6061.0f);
  double acc = 0.0;
  for (int p = tid; p < NPIX; p += 1024) {
    float term = (maskArr[p] > 0.0f) ? (logf(S[p]) + MSHIFT - logit0[p]) : cmask;
    acc += (double)term;
  }
#pragma unroll
  for (int off = 32; off; off >>= 1) acc += __shfl_down(acc, off, 64);
  __shared__ double sd[16];
  if ((tid & 63) == 0) sd[tid >> 6] = acc;
  __syncthreads();
  if (tid == 0) {
    double tot = 0.0;
    for (int w = 0; w < 16; w++) tot += sd[w];
    out[0] = (float)(tot / (double)NPIX);
  }
}

extern "C" void kernel_launch(void* const* d_in, const int* in_sizes, int n_in,
                              void* d_out, int out_size, void* d_ws, size_t ws_size,
                              hipStream_t stream) {
  const float* ref   = (const float*)d_in[0];
  const float* tgt   = (const float*)d_in[1];
  const float* tl    = (const float*)d_in[2];
  const float* tr    = (const float*)d_in[3];
  const float* queue = (const float*)d_in[4];
  float* out = (float*)d_out;
  float* ws = (float*)d_ws;

  float2* qeb = (float2*)ws;                 // 6144 float2 -> 12288 floats
  float* S    = ws + 12288;                  // 16384
  float* lg0  = ws + 28672;                  // 16384
  float* mk   = ws + 45056;                  // 16384
  float* xr   = ws + 61440;                  // 16384 -> 77824
  int* count  = (int*)(ws + 77824);          // 1
  int* list   = (int*)(ws + 77840);          // 16384 -> 94224
  _Float16* QTfc    = (_Float16*)(ws + 94464);    // NPIX*128 f16 (compacted rows)
  _Float16* queueTf = (_Float16*)(ws + 1143040);  // 6144*128 f16
  _Float16* tgtTf   = (_Float16*)(ws + 1536256);  // NPIX*128 f16
  _Float16* refTf   = (_Float16*)(ws + 2584832);  // NPIX*128 f16
  float* stats = ws + 3633408;                    // 2048
  _Float16* Dh = (_Float16*)(ws + 3635456);       // NPIX*256 f16

  // JAX: k1, k2 = split(key(1234))
  uint32_t b0o0, b0o1, b1o0, b1o1;
  threefry2x32(0u, 1234u, 0u, 2u, &b0o0, &b0o1);
  threefry2x32(0u, 1234u, 1u, 3u, &b1o0, &b1o1);
  uint32_t k1a = b0o0, k1b = b1o0, k2a = b0o1, k2b = b1o1;

  k_A<<<dim3(4952), dim3(256), 0, stream>>>(ref, tgt, queue, tl, tr,
                                            refTf, tgtTf, queueTf, qeb, mk, xr);
  k_compact<<<dim3(1), dim3(256), 0, stream>>>(mk, count, list);
  k_B<<<dim3(64 + 4096), dim3(256), 0, stream>>>(refTf, tgtTf, QTfc, stats,
                                                 xr, S, lg0, count, list);
  k_gemm<<<dim3(6, NPIX / 64), dim3(256), 0, stream>>>(QTfc, queueTf, tgtTf, qeb,
                                                       S, Dh, count, list);
  k_negatives_lite<<<dim3(NPIX / 4), dim3(256), 0, stream>>>(Dh, stats, xr, S, count, list,
                                                             k1a, k1b, k2a, k2b);
  k_finalize<<<dim3(1), dim3(1024), 0, stream>>>(S, lg0, mk, out);
}

// Round 17
// 131.963 us; speedup vs baseline: 1.0080x; 1.0066x over previous
//
#include <hip/hip_runtime.h>
#include <stdint.h>
#include <math.h>

#define HFM 64
#define WFM 128
#define CFM 128
#define BN 2
#define HWFM (HFM*WFM)          // 8192
#define NPIX (BN*HWFM)          // 16384
#define KQ 6000
#define KQP 6144                // padded to 48*128 (rows 6000..6143 zero)
#define NNEG 60
#define NE (NPIX*NNEG)          // 983040
#define EHALF_U 491520u
#define MSHIFT 15.0f
#define LOG2E 1.4426950408889634f
#define BSTRIDE 128             // LDS row stride in f16 (256 B) + XOR swizzle

typedef _Float16 f16_8 __attribute__((ext_vector_type(8)));
typedef _Float16 f16_2 __attribute__((ext_vector_type(2)));
typedef float f32_4 __attribute__((ext_vector_type(4)));

// ---------------- JAX threefry2x32 (bit-exact) ----------------
__host__ __device__ __forceinline__ void threefry2x32(uint32_t k0, uint32_t k1,
                                                      uint32_t x0, uint32_t x1,
                                                      uint32_t* o0, uint32_t* o1) {
  uint32_t ks2 = k0 ^ k1 ^ 0x1BD11BDAu;
  x0 += k0; x1 += k1;
#define TFR(r) { x0 += x1; x1 = (x1 << (r)) | (x1 >> (32 - (r))); x1 ^= x0; }
  TFR(13) TFR(15) TFR(26) TFR(6)
  x0 += k1;  x1 += ks2 + 1u;
  TFR(17) TFR(29) TFR(16) TFR(24)
  x0 += ks2; x1 += k0 + 2u;
  TFR(13) TFR(15) TFR(26) TFR(6)
  x0 += k0;  x1 += k1 + 3u;
  TFR(17) TFR(29) TFR(16) TFR(24)
  x0 += k1;  x1 += ks2 + 4u;
  TFR(13) TFR(15) TFR(26) TFR(6)
  x0 += ks2; x1 += k0 + 5u;
#undef TFR
  *o0 = x0; *o1 = x1;
}

// grid_sample coordinate helper (reference op order)
__device__ __forceinline__ void gs_coord(float t, float halfdim, float maxc,
                                         int* i0, int* i1, float* w) {
  float g = 2.0f * t - 1.0f;
  float x = (g + 1.0f) * halfdim - 0.5f;
  x = fminf(fmaxf(x, 0.0f), maxc);
  float f = floorf(x);
  *i0 = (int)f;
  *w = x - f;
  *i1 = (int)fminf(f + 1.0f, maxc);
}

// ====== k_A: mask (first, latency-bound) + qprep + qtrans + transpose ======
__global__ __launch_bounds__(256) void k_A(
    const float* __restrict__ ref, const float* __restrict__ tgt,
    const float* __restrict__ queue,
    const float* __restrict__ target_l, const float* __restrict__ target_r,
    _Float16* __restrict__ refTf, _Float16* __restrict__ tgtTf,
    _Float16* __restrict__ queueTf, float2* __restrict__ qeb,
    float* __restrict__ maskArr, float* __restrict__ xr) {
  __shared__ float tile[32][33];
  int blk = blockIdx.x;
  int tid = threadIdx.x;
  if (blk < 64) {
    // mask: one thread per pixel
    int p = blk * 256 + tid;
    int b = p >> 13;
    int rem = p & (HWFM - 1);
    int i = rem >> 7, j = rem & 127;
    const float stepx = 1.0f / 127.0f, stepy = 1.0f / 63.0f;
    float xb = (j == 127) ? 1.0f : j * stepx;
    float yb = (i == 63) ? 1.0f : i * stepy;
    const float* tl = target_l + (size_t)b * 256 * 512;
    const float* tr = target_r + (size_t)b * 256 * 512;
    float dl = tl[(4 * i) * 512 + 4 * j] * 0.25f;
    int y0i, y1i; float wy;
    gs_coord(yb, 32.0f, 63.0f, &y0i, &y1i, &wy);
    float t = xb - dl * (1.0f / 128.0f);
    int x0i, x1i; float wx;
    gs_coord(t, 64.0f, 127.0f, &x0i, &x1i, &wx);
    auto innerv = [&](int y, int x) -> float {
      float xbx = (x == 127) ? 1.0f : x * stepx;
      float drv = tr[(4 * y) * 512 + 4 * x] * 0.25f;
      float ti = xbx + drv * (1.0f / 128.0f);
      float g = 2.0f * ti - 1.0f;
      float ix2 = fminf(fmaxf((g + 1.0f) * 64.0f - 0.5f, 0.0f), 127.0f);
      float x0f = floorf(ix2);
      float wxp = ix2 - x0f;
      float x1f = fminf(x0f + 1.0f, 127.0f);
      return x0f * (1.0f - wxp) + x1f * wxp;
    };
    float v00 = innerv(y0i, x0i), v01 = innerv(y0i, x1i);
    float v10 = innerv(y1i, x0i), v11 = innerv(y1i, x1i);
    float l2r2l = v00 * (1.0f - wx) * (1.0f - wy) + v01 * wx * (1.0f - wy)
                + v10 * (1.0f - wx) * wy + v11 * wx * wy;
    bool masko = fabsf((float)j - l2r2l) < 3.0f;
    bool mk = masko && (dl > 0.0f) && (t >= 0.0f);
    maskArr[p] = mk ? 1.0f : 0.0f;
    xr[p] = t * 128.0f;   // exact: t*2^7
  } else if (blk < 88) {
    int k = (blk - 64) * 256 + tid;
    if (k < KQP) {
      if (k >= KQ) { qeb[k] = make_float2(0.0f, -1000.0f); }
      else {
        float ss = 0.0f;
        for (int c = 0; c < CFM; c++) { float v = queue[c * KQ + k]; ss += v * v; }
        float qi = 1.0f / fmaxf(sqrtf(ss), 1e-12f);
        qeb[k] = make_float2(qi * (LOG2E / 0.07f), -MSHIFT * LOG2E);
      }
    }
  } else if (blk < 856) {
    int q = blk - 88;
    int cy = q / 192, nx = q - cy * 192;
    int n0 = nx * 32, c0 = cy * 32;
    int tx = tid & 31, ty = tid >> 5;
#pragma unroll
    for (int i = 0; i < 32; i += 8) {
      int n = n0 + tx;
      tile[ty + i][tx] = (n < KQ) ? queue[(size_t)(c0 + ty + i) * KQ + n] : 0.0f;
    }
    __syncthreads();
#pragma unroll
    for (int i = 0; i < 32; i += 8)
      queueTf[(size_t)(n0 + ty + i) * CFM + (c0 + tx)] = (_Float16)tile[tx][ty + i];
  } else {
    int fblk = blk - 856;
    int z = fblk >> 10, yb_ = (fblk >> 8) & 3, xb_ = fblk & 255;
    int arr = z >> 1, b = z & 1;
    const float* src = (arr == 0 ? ref : tgt) + (size_t)b * CFM * HWFM;
    _Float16* dst = (arr == 0 ? refTf : tgtTf) + (size_t)b * HWFM * CFM;
    int x0 = xb_ * 32, y0 = yb_ * 32;
    int tx = tid & 31, ty = tid >> 5;
#pragma unroll
    for (int i = 0; i < 32; i += 8)
      tile[ty + i][tx] = src[(size_t)(y0 + ty + i) * HWFM + x0 + tx];
    __syncthreads();
#pragma unroll
    for (int i = 0; i < 32; i += 8)
      dst[(size_t)(x0 + ty + i) * CFM + (y0 + tx)] = (_Float16)tile[tx][ty + i];
  }
}

// ====== k_B: compact (block 0) + colstats (1..64) + prelude p-indexed ======
__global__ __launch_bounds__(256) void k_B(
    const _Float16* __restrict__ refTf, const _Float16* __restrict__ tgtTf,
    _Float16* __restrict__ QTf, float* __restrict__ stats,
    const float* __restrict__ maskArr, const float* __restrict__ xr,
    float* __restrict__ S, float* __restrict__ logit0,
    int* __restrict__ count, int* __restrict__ list) {
  __shared__ int wsum[4];
  int blk = blockIdx.x;
  int tid = threadIdx.x;
  int lane = tid & 63;
  if (blk == 0) {
    // compact: thread handles 64 consecutive pixels
    int wave = tid >> 6;
    int base_p = tid * 64;
    unsigned long long bits = 0ull;
    const float4* m4 = (const float4*)(maskArr + base_p);
#pragma unroll
    for (int k = 0; k < 16; k++) {
      float4 v = m4[k];
      if (v.x > 0.0f) bits |= 1ull << (4 * k + 0);
      if (v.y > 0.0f) bits |= 1ull << (4 * k + 1);
      if (v.z > 0.0f) bits |= 1ull << (4 * k + 2);
      if (v.w > 0.0f) bits |= 1ull << (4 * k + 3);
    }
    int m = __popcll(bits);
    int scan = m;
#pragma unroll
    for (int off = 1; off < 64; off <<= 1) {
      int n = __shfl_up(scan, off, 64);
      if (lane >= off) scan += n;
    }
    if (lane == 63) wsum[wave] = scan;
    __syncthreads();
    int wbase = 0;
    for (int w = 0; w < wave; w++) wbase += wsum[w];
    int idx = wbase + scan - m;
    for (int k = 0; k < 64; k++) {
      if ((bits >> k) & 1ull) list[idx++] = base_p + k;
    }
    if (tid == 255) *count = idx;
  } else if (blk < 65) {
    int sub = tid >> 6;
    int xg = (blk - 1) * 4 + sub;
    int b = xg >> 7, x = xg & 127;
    int xp = min(x + 1, 127);
    int c2 = lane * 2;
    int base = b * HWFM;
    f16_2 c0  = *(const f16_2*)(tgtTf + (size_t)(base + x) * CFM + c2);
    f16_2 c1  = *(const f16_2*)(tgtTf + (size_t)(base + WFM + x) * CFM + c2);
    f16_2 c0p = *(const f16_2*)(tgtTf + (size_t)(base + xp) * CFM + c2);
    f16_2 c1p = *(const f16_2*)(tgtTf + (size_t)(base + WFM + xp) * CFM + c2);
    float a0 = (float)c0[0], a1 = (float)c0[1];
    float b0 = (float)c1[0], b1 = (float)c1[1];
    float p0 = (float)c0p[0], p1 = (float)c0p[1];
    float q0 = (float)c1p[0], q1 = (float)c1p[1];
    float s[7];
    s[0] = a0 * a0 + a1 * a1;
    s[1] = a0 * b0 + a1 * b1;
    s[2] = b0 * b0 + b1 * b1;
    s[3] = a0 * p0 + a1 * p1;
    s[4] = a0 * q0 + a1 * q1;
    s[5] = b0 * p0 + b1 * p1;
    s[6] = b0 * q0 + b1 * q1;
#pragma unroll
    for (int o = 32; o; o >>= 1)
#pragma unroll
      for (int k = 0; k < 7; k++) s[k] += __shfl_xor(s[k], o, 64);
    if (lane == 0) {
      float* st = stats + (size_t)xg * 8;
#pragma unroll
      for (int k = 0; k < 7; k++) st[k] = s[k];
      st[7] = 0.0f;
    }
  } else {
    // prelude: wave per pixel p (p-indexed), early-exit masked
    int wave = tid >> 6;
    int p = (blk - 65) * 4 + wave;
    float mk = maskArr[p];
    if (mk == 0.0f) return;
    int b = p >> 13;
    int rem = p & (HWFM - 1);
    int i = rem >> 7;
    const float stepy = 1.0f / 63.0f;
    float yb = (i == 63) ? 1.0f : i * stepy;
    float t = xr[p] * (1.0f / 128.0f);   // exact recovery
    int y0i, y1i; float wy;
    gs_coord(yb, 32.0f, 63.0f, &y0i, &y1i, &wy);
    int x0i, x1i; float wx;
    gs_coord(t, 64.0f, 127.0f, &x0i, &x1i, &wx);

    int c2 = lane * 2;
    f16_2 q2 = *(const f16_2*)(refTf + (size_t)p * CFM + c2);
    int bo = b * HWFM;
    f16_2 a2 = *(const f16_2*)(tgtTf + (size_t)(bo + y0i * WFM + x0i) * CFM + c2);
    f16_2 b2 = *(const f16_2*)(tgtTf + (size_t)(bo + y0i * WFM + x1i) * CFM + c2);
    f16_2 cc2 = *(const f16_2*)(tgtTf + (size_t)(bo + y1i * WFM + x0i) * CFM + c2);
    f16_2 d2 = *(const f16_2*)(tgtTf + (size_t)(bo + y1i * WFM + x1i) * CFM + c2);

    float w00 = (1.0f - wx) * (1.0f - wy), w01 = wx * (1.0f - wy);
    float w10 = (1.0f - wx) * wy,          w11 = wx * wy;
    float q0 = (float)q2[0], q1 = (float)q2[1];
    float v0 = w00 * (float)a2[0] + w01 * (float)b2[0] + w10 * (float)cc2[0] + w11 * (float)d2[0];
    float v1 = w00 * (float)a2[1] + w01 * (float)b2[1] + w10 * (float)cc2[1] + w11 * (float)d2[1];

    float s0 = q0 * q0 + q1 * q1;
    float s1 = q0 * v0 + q1 * v1;
    float s2 = v0 * v0 + v1 * v1;
#pragma unroll
    for (int o = 32; o; o >>= 1) {
      s0 += __shfl_xor(s0, o, 64);
      s1 += __shfl_xor(s1, o, 64);
      s2 += __shfl_xor(s2, o, 64);
    }
    float inv = 1.0f / fmaxf(sqrtf(s0), 1e-12f);
    f16_2 qw; qw[0] = (_Float16)(q0 * inv); qw[1] = (_Float16)(q1 * inv);
    *(f16_2*)(QTf + (size_t)p * CFM + c2) = qw;
    if (lane == 0) {
      float lpos = (s1 * inv) / fmaxf(sqrtf(s2), 1e-12f);
      float lg0 = lpos / 0.07f;
      logit0[p] = lg0;
      S[p] = expf(lg0 - MSHIFT);
    }
  }
}

// ======== k_gemm: 64-row tile, 8 chunks/block, pipelined LDS double-buffer ====
// with XOR-swizzled 256B rows (conflict-free ds_read_b128). grid (6, 256).
// Pipeline: issue next chunk's global loads -> MFMA current chunk -> ds_write.
__global__ __launch_bounds__(256) void k_gemm(
    const _Float16* __restrict__ QTf,     // [NPIX][128] (p-indexed)
    const _Float16* __restrict__ queueTf, // [6144][128]
    const _Float16* __restrict__ tgtTf,   // [NPIX][128]
    const float2* __restrict__ qeb,       // [6144]
    float* __restrict__ S, float* __restrict__ D,
    const int* __restrict__ count, const int* __restrict__ list) {
  __shared__ _Float16 Bs[2][128 * BSTRIDE];   // 2 x 32768 B
  __shared__ float Srow[64];
  __shared__ int pb[64];
  int tid = threadIdx.x;
  int cnt = *count;
  int pblk = blockIdx.y * 64;
  if (pblk >= cnt) return;
  int wave = tid >> 6, lane = tid & 63;
  int quad = lane >> 4, l16 = lane & 15;
  int wm = wave >> 1, wn = wave & 1;

  if (tid < 64) {
    Srow[tid] = 0.0f;
    pb[tid] = list[min(pblk + tid, cnt - 1)] >> 13;
  }

  // A fragments via list indirection
  f16_8 Af[2][4];
  int r0 = pblk + wm * 32;
#pragma unroll
  for (int mt = 0; mt < 2; mt++) {
    int prow = list[min(r0 + mt * 16 + l16, cnt - 1)];
    const _Float16* arow = QTf + (size_t)prow * CFM + quad * 8;
#pragma unroll
    for (int ks = 0; ks < 4; ks++)
      Af[mt][ks] = *(const f16_8*)(arow + ks * 32);
  }

  f16_8 sreg[8];
  int srow[8], scol[8], sc16raw[8];
#pragma unroll
  for (int it = 0; it < 8; it++) {
    int idx = it * 256 + tid;
    int row = idx >> 4, c16 = idx & 15;
    srow[it] = row;
    sc16raw[it] = c16 * 8;
    scol[it] = (c16 ^ (row & 15)) * 8;   // XOR swizzle
  }
  auto load_src = [&](const _Float16* bsrc) {
#pragma unroll
    for (int it = 0; it < 8; it++)
      sreg[it] = *(const f16_8*)(bsrc + (size_t)srow[it] * CFM + sc16raw[it]);
  };
  auto write_lds = [&](int buf) {
#pragma unroll
    for (int it = 0; it < 8; it++)
      *(f16_8*)(&Bs[buf][srow[it] * BSTRIDE + scol[it]]) = sreg[it];
  };
  auto read_b = [&](int buf, int rl, int ks) -> f16_8 {
    int col = ((ks * 4 + quad) ^ (rl & 15)) * 8;
    return *(const f16_8*)(&Bs[buf][rl * BSTRIDE + col]);
  };

  int nbase = blockIdx.x * 8 * 128;
  int cur;
  float rowsum[2][4] = {{0.0f,0.0f,0.0f,0.0f},{0.0f,0.0f,0.0f,0.0f}};

  if (blockIdx.x < 4) {
    // D chunk
    int batch = blockIdx.x >> 1;
    load_src(tgtTf + ((size_t)batch * HWFM + (blockIdx.x & 1) * 128) * CFM);
    write_lds(0);
    __syncthreads();
    // prefetch l_q chunk 0 while computing D
    load_src(queueTf + (size_t)nbase * CFM);
    f32_4 acc[2][4];
#pragma unroll
    for (int mt = 0; mt < 2; mt++)
#pragma unroll
      for (int nt = 0; nt < 4; nt++)
        acc[mt][nt] = (f32_4){0.0f, 0.0f, 0.0f, 0.0f};
#pragma unroll
    for (int ks = 0; ks < 4; ks++) {
      f16_8 Bk[4];
#pragma unroll
      for (int nt = 0; nt < 4; nt++)
        Bk[nt] = read_b(0, wn * 64 + nt * 16 + l16, ks);
#pragma unroll
      for (int mt = 0; mt < 2; mt++)
#pragma unroll
        for (int nt = 0; nt < 4; nt++)
          acc[mt][nt] = __builtin_amdgcn_mfma_f32_16x16x32_f16(Af[mt][ks], Bk[nt], acc[mt][nt], 0, 0, 0);
    }
#pragma unroll
    for (int mt = 0; mt < 2; mt++)
#pragma unroll
      for (int nt = 0; nt < 4; nt++)
#pragma unroll
        for (int r = 0; r < 4; r++) {
          int rowloc = wm * 32 + mt * 16 + quad * 4 + r;
          int slot = pblk + rowloc;
          int colL = (blockIdx.x & 1) * 128 + wn * 64 + nt * 16 + l16;
          if (slot < cnt && pb[rowloc] == batch)
            D[(size_t)slot * 256 + colL] = acc[mt][nt][r];
        }
    write_lds(1);
    __syncthreads();
    cur = 1;
  } else {
    load_src(queueTf + (size_t)nbase * CFM);
    write_lds(0);
    __syncthreads();
    cur = 0;
  }

#pragma unroll
  for (int ic = 0; ic < 8; ic++) {
    int n0 = nbase + ic * 128;
    if (ic + 1 < 8) load_src(queueTf + (size_t)(n0 + 128) * CFM);
    float2 qb[4];
#pragma unroll
    for (int nt = 0; nt < 4; nt++) qb[nt] = qeb[n0 + wn * 64 + nt * 16 + l16];

    f32_4 acc[2][4];
#pragma unroll
    for (int mt = 0; mt < 2; mt++)
#pragma unroll
      for (int nt = 0; nt < 4; nt++)
        acc[mt][nt] = (f32_4){0.0f, 0.0f, 0.0f, 0.0f};
#pragma unroll
    for (int ks = 0; ks < 4; ks++) {
      f16_8 Bk[4];
#pragma unroll
      for (int nt = 0; nt < 4; nt++)
        Bk[nt] = read_b(cur, wn * 64 + nt * 16 + l16, ks);
#pragma unroll
      for (int mt = 0; mt < 2; mt++)
#pragma unroll
        for (int nt = 0; nt < 4; nt++)
          acc[mt][nt] = __builtin_amdgcn_mfma_f32_16x16x32_f16(Af[mt][ks], Bk[nt], acc[mt][nt], 0, 0, 0);
    }
    if (ic + 1 < 8) write_lds(cur ^ 1);   // vmcnt wait lands here, after compute

#pragma unroll
    for (int nt = 0; nt < 4; nt++)
#pragma unroll
      for (int mt = 0; mt < 2; mt++)
#pragma unroll
        for (int r = 0; r < 4; r++)
          rowsum[mt][r] += exp2f(fmaf(acc[mt][nt][r], qb[nt].x, qb[nt].y));
    __syncthreads();
    cur ^= 1;
  }

#pragma unroll
  for (int mt = 0; mt < 2; mt++)
#pragma unroll
    for (int r = 0; r < 4; r++) {
      float vv = rowsum[mt][r];
      vv += __shfl_xor(vv, 1);
      vv += __shfl_xor(vv, 2);
      vv += __shfl_xor(vv, 4);
      vv += __shfl_xor(vv, 8);
      rowsum[mt][r] = vv;
    }
  if (l16 == 0) {
#pragma unroll
    for (int mt = 0; mt < 2; mt++)
#pragma unroll
      for (int r = 0; r < 4; r++)
        atomicAdd(&Srow[wm * 32 + mt * 16 + quad * 4 + r], rowsum[mt][r]);
  }
  __syncthreads();
  if (tid < 64) {
    int pr = pblk + tid;
    if (pr < cnt) atomicAdd(&S[list[pr]], Srow[tid]);
  }
}

// -------- negatives: wave-per-pixel, scalar via D + stats decomposition ----
__global__ __launch_bounds__(256) void k_negatives_lite(
    const float* __restrict__ D, const float* __restrict__ stats,
    const float* __restrict__ xr, float* __restrict__ S,
    const int* __restrict__ count, const int* __restrict__ list,
    uint32_t k1a, uint32_t k1b, uint32_t k2a, uint32_t k2b) {
  int tid = threadIdx.x;
  int wave = tid >> 6, lane = tid & 63;
  int cnt = *count;
  int slot = blockIdx.x * 4 + wave;
  if (slot >= cnt) return;
  int p = list[slot];
  int b = p >> 13;
  float esum = 0.0f;
  if (lane < NNEG) {
    uint32_t e = (uint32_t)(p * NNEG + lane);
    uint32_t h0, h1;
    threefry2x32(k1a, k1b, e, e + (uint32_t)NE, &h0, &h1);
    uint32_t off = ((h0 % 24u) * 16u + (h1 % 24u)) % 24u;
    float mag = (float)(1u + off);
    uint32_t ub;
    {
      uint32_t a, bm;
      if (e < EHALF_U) { threefry2x32(k2a, k2b, e, e + EHALF_U, &a, &bm); ub = a; }
      else             { threefry2x32(k2a, k2b, e - EHALF_U, e, &a, &bm); ub = bm; }
    }
    float u = __uint_as_float((ub >> 9) | 0x3F800000u) - 1.0f;
    float sg = (u > 0.5f) ? 1.0f : ((u < 0.5f) ? -1.0f : 0.0f);

    float v = xr[p] + mag * sg;
    float r = fmodf(v, 128.0f);
    if (r < 0.0f) r += 128.0f;
    float fx = r * (1.0f / 128.0f);
    float fy = fx * (1.0f / 64.0f);
    int x0i, x1i, y0i, y1i; float wx, wy;
    gs_coord(fx, 64.0f, 127.0f, &x0i, &x1i, &wx);
    gs_coord(fy, 32.0f, 63.0f, &y0i, &y1i, &wy);

    const float* Dp = D + (size_t)slot * 256;
    float d00 = Dp[x0i], d01 = Dp[x1i];
    float d10 = Dp[128 + x0i], d11 = Dp[128 + x1i];
    float u0 = 1.0f - wy, u1 = wy;
    float dv0 = u0 * d00 + u1 * d10;
    float dv1 = u0 * d01 + u1 * d11;
    float dot = (1.0f - wx) * dv0 + wx * dv1;

    const float* st0 = stats + (size_t)(b * 128 + x0i) * 8;
    const float* st1 = stats + (size_t)(b * 128 + x1i) * 8;
    float4 sa = *(const float4*)st0;
    float4 sb = *(const float4*)(st0 + 4);
    float4 sc = *(const float4*)st1;
    float a0 = u0 * u0, a1 = u0 * u1, a2 = u1 * u1;
    float nB0 = a0 * sa.x + 2.0f * a1 * sa.y + a2 * sa.z;
    float nB1 = a0 * sc.x + 2.0f * a1 * sc.y + a2 * sc.z;
    float cB  = a0 * sa.w + a1 * (sb.x + sb.y) + a2 * sb.z;
    float wx0 = 1.0f - wx;
    float nsq = wx0 * wx0 * nB0 + 2.0f * wx * wx0 * cB + wx * wx * nB1;
    float ln = dot / fmaxf(sqrtf(fmaxf(nsq, 0.0f)), 1e-12f);
    esum = __expf(ln * (1.0f / 0.07f) - MSHIFT);
  }
#pragma unroll
  for (int o = 32; o; o >>= 1) esum += __shfl_xor(esum, o, 64);
  if (lane == 0) atomicAdd(&S[p], esum);
}

__global__ __launch_bounds__(1024) void k_finalize(
    const float* __restrict__ S, const float* __restrict__ logit0,
    const float* __restrict__ maskArr, float* __restrict__ out) {
  int tid = threadIdx.x;
  const float cmask = logf(6061.0f);
  double acc = 0.0;
  for (int p = tid; p < NPIX; p += 1024) {
    float term = (maskArr[p] > 0.0f) ? (logf(S[p]) + MSHIFT - logit0[p]) : cmask;
    acc += (double)term;
  }
#pragma unroll
  for (int off = 32; off; off >>= 1) acc += __shfl_down(acc, off, 64);
  __shared__ double sd[16];
  if ((tid & 63) == 0) sd[tid >> 6] = acc;
  __syncthreads();
  if (tid == 0) {
    double tot = 0.0;
    for (int w = 0; w < 16; w++) tot += sd[w];
    out[0] = (float)(tot / (double)NPIX);
  }
}

extern "C" void kernel_launch(void* const* d_in, const int* in_sizes, int n_in,
                              void* d_out, int out_size, void* d_ws, size_t ws_size,
                              hipStream_t stream) {
  const float* ref   = (const float*)d_in[0];
  const float* tgt   = (const float*)d_in[1];
  const float* tl    = (const float*)d_in[2];
  const float* tr    = (const float*)d_in[3];
  const float* queue = (const float*)d_in[4];
  float* out = (float*)d_out;
  float* ws = (float*)d_ws;

  float2* qeb = (float2*)ws;                 // 6144 float2 -> 12288 floats
  float* S    = ws + 12288;                  // 16384
  float* lg0  = ws + 28672;                  // 16384
  float* mk   = ws + 45056;                  // 16384
  float* xr   = ws + 61440;                  // 16384 -> 77824
  int* count  = (int*)(ws + 77824);          // 1
  int* list   = (int*)(ws + 77840);          // 16384 -> 94224
  _Float16* QTf     = (_Float16*)(ws + 94464);    // NPIX*128 f16 (p-indexed)
  _Float16* queueTf = (_Float16*)(ws + 1143040);  // 6144*128 f16
  _Float16* tgtTf   = (_Float16*)(ws + 1536256);  // NPIX*128 f16
  _Float16* refTf   = (_Float16*)(ws + 2584832);  // NPIX*128 f16
  float* stats = ws + 3633408;                    // 2048
  float* D     = ws + 3635456;                    // NPIX*256 f32

  // JAX: k1, k2 = split(key(1234))
  uint32_t b0o0, b0o1, b1o0, b1o1;
  threefry2x32(0u, 1234u, 0u, 2u, &b0o0, &b0o1);
  threefry2x32(0u, 1234u, 1u, 3u, &b1o0, &b1o1);
  uint32_t k1a = b0o0, k1b = b1o0, k2a = b0o1, k2b = b1o1;

  k_A<<<dim3(4952), dim3(256), 0, stream>>>(ref, tgt, queue, tl, tr,
                                            refTf, tgtTf, queueTf, qeb, mk, xr);
  k_B<<<dim3(65 + 4096), dim3(256), 0, stream>>>(refTf, tgtTf, QTf, stats,
                                                 mk, xr, S, lg0, count, list);
  k_gemm<<<dim3(6, NPIX / 64), dim3(256), 0, stream>>>(QTf, queueTf, tgtTf, qeb,
                                                       S, D, count, list);
  k_negatives_lite<<<dim3(NPIX / 4), dim3(256), 0, stream>>>(D, stats, xr, S, count, list,
                                                             k1a, k1b, k2a, k2b);
  k_finalize<<<dim3(1), dim3(1024), 0, stream>>>(S, lg0, mk, out);
}